// Round 19
// baseline (71.438 us; speedup 1.0000x reference)
//
#include <hip/hip_runtime.h>
#include <cstdint>
#include <cstddef>

typedef _Float16 f16x8 __attribute__((ext_vector_type(8)));
typedef _Float16 f16x4 __attribute__((ext_vector_type(4)));
typedef float    f32x4 __attribute__((ext_vector_type(4)));

#define MFMA16(a,b,c) __builtin_amdgcn_mfma_f32_16x16x32_f16((a),(b),(c),0,0,0)

// ws layout (halfs) — weights in 16x16-MFMA fragment-linear order (R12..R18-verified):
//   W1F  [15][4ot][8kk][64][8] @0       (245760)
//   W16F [4ot][12kk][64][8]    @245760  (24576)   sp=32kk+8(l>>4)+j; x col=1808+sp; zero sp<12 or sp>=368
//   W2F  [16t][8kk][64][8]     @270336  (65536)
//   W3F  [17t][8kk][64][8]     @335872  (69632)   o>=260 zero
__global__ void tea_prep(const float* __restrict__ W1, const float* __restrict__ W16,
                         const float* __restrict__ W2, const float* __restrict__ W3,
                         _Float16* __restrict__ ws)
{
    int i = blockIdx.x * blockDim.x + threadIdx.x;
    if (i < 245760) {
        int win = i >> 14, t = i & 16383;
        int ot = t >> 12, kk = (t >> 9) & 7, l = (t >> 3) & 63, j = t & 7;
        int o = 16 * ot + (l & 15);
        int s = 32 * kk + 8 * (l >> 4) + j;
        ws[i] = (_Float16)W1[(win * 256 + s) * 64 + o];
    } else if (i < 270336) {
        int t = i - 245760;
        int ot = t / 6144, t2 = t % 6144;
        int kk = t2 >> 9, l = (t2 >> 3) & 63, j = t2 & 7;
        int o = 16 * ot + (l & 15);
        int sp = 32 * kk + 8 * (l >> 4) + j;
        ws[i] = (_Float16)((sp >= 12 && sp < 368) ? W16[(sp - 12) * 64 + o] : 0.f);
    } else if (i < 335872) {
        int t = i - 270336;
        int q2 = t >> 12, kk = (t >> 9) & 7, l = (t >> 3) & 63, j = t & 7;
        int og = 16 * q2 + (l & 15);
        int g = q2 >> 2, o2 = og - 64 * g;
        int s = 32 * kk + 8 * (l >> 4) + j;
        ws[i] = (_Float16)W2[(g * 256 + s) * 64 + o2];
    } else if (i < 405504) {
        int t = i - 335872;
        int tt = t >> 12, kk = (t >> 9) & 7, l = (t >> 3) & 63, j = t & 7;
        int o = 16 * tt + (l & 15);
        int s = 32 * kk + 8 * (l >> 4) + j;
        ws[i] = (_Float16)((o < 260) ? W3[s * 260 + o] : 0.f);
    }
}

// Producer/consumer fused kernel, 64 rows/block, 256 blocks (1/CU, SINGLE generation).
//   waves 8..15: producers — x global->reg(4 buffers)->cvt fp16->swizzled ds_write
//   waves 0..7 : consumers — weight frags + MFMA (x already fp16 in LDS)
// R19 change vs R18: producer QUAD-buffered (chunk c -> buffer c%4); pass p ploads
// chunks 2p+7, 2p+8 so every pwrite consumes a load aged 2 passes; 16 dwordx4/wave
// in flight. Ring write/read schedule identical to R18 (deadness proof unchanged).
// LDS sh[74752] halfs = 149504 B:
//   ring: 5 slots x [64 rows][256 B] fp16 chunks, bytes [0, 81920)
//         swizzle: byte-in-row ^= (row&15)<<4 (write AND read side)
//   ygrp: f16 [64][264], halfs [40960, 57856)   current group's y (4 wins x 64)
//   zsm : f16 [64][264], halfs [57856, 74752)
//   ps  : f32 [17][64][10], bytes [0, 43520)    alias ring (written in l3; ring dead)
__global__ __launch_bounds__(1024, 4)
void tea_dma(const float* __restrict__ x,
             const float* __restrict__ b1,  const float* __restrict__ b16,
             const float* __restrict__ b2,  const float* __restrict__ b3,
             const _Float16* __restrict__ ws, float* __restrict__ out)
{
    __shared__ _Float16 sh[74752];
    char* shb = (char*)sh;

    const int tid = threadIdx.x;
    const int bid = blockIdx.x;
    const int wg  = (bid & 7) * 32 + (bid >> 3);      // bijective XCD swizzle (256%8==0)
    const int q = tid >> 6, l = tid & 63, r = l & 15, kg = l >> 4;
    const bool prod = (q >= 8);
    const int  pw   = q - 8;                          // producer wave id 0..7

    const float* xf = x + (size_t)wg * 64 * 2176;

    // ---- producer staging: QUAD-buffered regs (chunk c -> buffer c%4) ----
    float4 B0[4], B1[4], B2[4], B3[4];
    const int prow = 8 * pw + (l >> 3);               // lane's batch row (0..63)
    const int pcol = (l & 7) * 16;                    // lane's fp32 col base in chunk

    auto pload = [&](int c, float4* S) {
        const float* p = xf + (size_t)prow * 2176 + c * 128 + pcol;
        S[0] = *(const float4*)(p);
        S[1] = *(const float4*)(p + 4);
        S[2] = *(const float4*)(p + 8);
        S[3] = *(const float4*)(p + 12);
    };
    auto pwrite = [&](int c, float4* S) {
        const int swz  = (prow & 15) << 4;
        const int colb = pcol * 2;                    // byte offset of lane's 16 halfs
        char* base = shb + (c % 5) * 16384 + prow * 256;
        f16x8 h0, h1;
        h0[0]=(_Float16)S[0].x; h0[1]=(_Float16)S[0].y; h0[2]=(_Float16)S[0].z; h0[3]=(_Float16)S[0].w;
        h0[4]=(_Float16)S[1].x; h0[5]=(_Float16)S[1].y; h0[6]=(_Float16)S[1].z; h0[7]=(_Float16)S[1].w;
        h1[0]=(_Float16)S[2].x; h1[1]=(_Float16)S[2].y; h1[2]=(_Float16)S[2].z; h1[3]=(_Float16)S[2].w;
        h1[4]=(_Float16)S[3].x; h1[5]=(_Float16)S[3].y; h1[6]=(_Float16)S[3].z; h1[7]=(_Float16)S[3].w;
        *(f16x8*)(base + (colb ^ swz))        = h0;
        *(f16x8*)(base + ((colb + 16) ^ swz)) = h1;
    };

#define BARL() do { \
    asm volatile("s_waitcnt lgkmcnt(0)" ::: "memory"); \
    __builtin_amdgcn_s_barrier(); \
    __builtin_amdgcn_sched_barrier(0); } while (0)

    // ring B-frag (fp16): one ds_read_b128, read-side XOR matches pwrite's
    auto bfrag = [&](int slotb, int rowloc, int colb) -> f16x8 {
        int swz = (rowloc & 15) << 4;
        return *(const f16x8*)(shb + slotb + rowloc * 256 + (colb ^ swz));
    };

    // consumer: persistent A-fragment set, prefetched one pass ahead
    f16x8 Afn[8];
    const int wq = q >> 2;                            // consumer: window-of-pair (0/1)
    if (!prod) {
        const _Float16* A0 = ws + wq * 16384 + (q & 3) * 4096;
        #pragma unroll
        for (int kk = 0; kk < 8; ++kk)
            Afn[kk] = *(const f16x8*)(A0 + kk * 512 + l * 8);
    }

    auto ystore = [&](int rh, int winp, f32x4 a, float4 bv) {
        f16x4 pk;
        pk[0] = (_Float16)fmaxf(a[0] + bv.x, 0.f);
        pk[1] = (_Float16)fmaxf(a[1] + bv.y, 0.f);
        pk[2] = (_Float16)fmaxf(a[2] + bv.z, 0.f);
        pk[3] = (_Float16)fmaxf(a[3] + bv.w, 0.f);
        *(f16x4*)&sh[40960 + (16 * rh + r) * 264 + 64 * winp + 16 * (q & 3) + 4 * kg] = pk;
    };

    // consumer window job: (win, ot=q&3), ALL FOUR row-quarters interleaved
    auto wincomp = [&](int win, const float* bp, int nextwin) {
        float4 bv = *(const float4*)(bp + 16 * (q & 3) + 4 * kg);
        f32x4 a0 = {0.f,0.f,0.f,0.f}, a1 = a0, a2 = a0, a3 = a0;
        __builtin_amdgcn_s_setprio(1);
        #pragma unroll
        for (int kk = 0; kk < 8; ++kk) {
            int slotb = ((win + (kk >> 2)) % 5) * 16384;
            int colb  = 64 * (kk & 3) + 16 * kg;
            a0 = MFMA16(Afn[kk], bfrag(slotb,      r, colb), a0);
            a1 = MFMA16(Afn[kk], bfrag(slotb, 16 + r, colb), a1);
            a2 = MFMA16(Afn[kk], bfrag(slotb, 32 + r, colb), a2);
            a3 = MFMA16(Afn[kk], bfrag(slotb, 48 + r, colb), a3);
        }
        __builtin_amdgcn_s_setprio(0);
        if (nextwin >= 0) {
            const _Float16* An = ws + nextwin * 16384 + (q & 3) * 4096;
            #pragma unroll
            for (int kk = 0; kk < 8; ++kk)
                Afn[kk] = *(const f16x8*)(An + kk * 512 + l * 8);
        }
        ystore(0, win & 3, a0, bv);
        ystore(1, win & 3, a1, bv);
        ystore(2, win & 3, a2, bv);
        ystore(3, win & 3, a3, bv);
    };

    // win14 single row-quarter (pass 7); uses Afn prefetched with nextwin=14
    auto win14c = [&](int rh) {
        float4 bv = *(const float4*)(b1 + 14 * 64 + 16 * (q & 3) + 4 * kg);
        f32x4 acc = {0.f,0.f,0.f,0.f};
        #pragma unroll
        for (int kk = 0; kk < 8; ++kk) {
            int slotb = ((14 + (kk >> 2)) % 5) * 16384;
            int colb  = 64 * (kk & 3) + 16 * kg;
            acc = MFMA16(Afn[kk], bfrag(slotb, 16 * rh + r, colb), acc);
        }
        ystore(rh, 2, acc, bv);
    };

    // y16 tail: K=368 from x col 1808 (chunk-14 half-offset 16); chunks 14,15,16
    auto y16c = [&](int rh) {
        const _Float16* A = ws + 245760 + (q & 3) * 6144;
        f32x4 acc = {0.f,0.f,0.f,0.f};
        #pragma unroll
        for (int kk = 0; kk < 12; ++kk) {
            int offh = 16 + 32 * kk + 8 * kg;         // half-offset from chunk-14 base
            if (32 * kk + 8 * kg >= 368) offh = 376;  // sp>=368 -> zero weights
            int cc = offh >> 7;                       // 0,1,2 -> chunks 14,15,16
            int slotb = ((14 + cc) % 5) * 16384;      // slots 4,0,1
            int colb  = (offh & 127) * 2;
            f16x8 Af = *(const f16x8*)(A + kk * 512 + l * 8);
            acc = MFMA16(Af, bfrag(slotb, 16 * rh + r, colb), acc);
        }
        float4 bv = *(const float4*)(b16 + 16 * (q & 3) + 4 * kg);
        ystore(rh, 3, acc, bv);
    };

    // layer-2 group g (consumers): t = 4g+(q&3); row-quarters q>>2 and q>>2+2
    auto l2group = [&](int g) {
        if (q < 8) {
            int t = 4 * g + (q & 3);
            const _Float16* A = ws + 270336 + t * 4096;
            float4 bv = *(const float4*)(b2 + 16 * t + 4 * kg);
            #pragma unroll
            for (int rr = 0; rr < 2; ++rr) {
                int rh2 = (q >> 2) + 2 * rr;
                f32x4 acc = {0.f,0.f,0.f,0.f};
                #pragma unroll
                for (int kk = 0; kk < 8; ++kk) {
                    f16x8 B  = *(const f16x8*)&sh[40960 + (16 * rh2 + r) * 264 + 32 * kk + 8 * kg];
                    f16x8 Af = *(const f16x8*)(A + kk * 512 + l * 8);
                    acc = MFMA16(Af, B, acc);
                }
                f16x4 pk;
                pk[0] = (_Float16)fmaxf(acc[0] + bv.x, 0.f);
                pk[1] = (_Float16)fmaxf(acc[1] + bv.y, 0.f);
                pk[2] = (_Float16)fmaxf(acc[2] + bv.z, 0.f);
                pk[3] = (_Float16)fmaxf(acc[3] + bv.w, 0.f);
                *(f16x4*)&sh[57856 + (16 * rh2 + r) * 264 + 16 * t + 4 * kg] = pk;
            }
        }
    };

    // ---- prologue: chunks 0-2 staged; buffers hold chunks 3,4,5,6 ----
    if (prod) {
        pload(0, B0); pload(1, B1); pload(2, B2); pload(3, B3);
        pwrite(0, B0); pwrite(1, B1); pwrite(2, B2);
        pload(4, B0); pload(5, B1); pload(6, B2);
    }

    // ---- l1: 8 passes (window pairs), l2 groups interleaved ----
    // pass p: pwrite chunks 2p+3 (buf (2p+3)%4), 2p+4 (buf (2p+4)%4);
    //         pload chunks 2p+7, 2p+8 into the same two buffers (aged 2 passes).
    BARL();                                            // pass 0: chunks 0-2 ready
    if (prod) { pwrite(3, B3); pwrite(4, B0); pload(7, B3); pload(8, B0); }
    else      wincomp(wq, b1 + wq * 64, 2 + wq);
    BARL();                                            // pass 1
    if (prod) { pwrite(5, B1); pwrite(6, B2); pload(9, B1); pload(10, B2); }
    else      wincomp(2 + wq, b1 + (2 + wq) * 64, 4 + wq);
    BARL(); l2group(0);
    BARL();                                            // pass 2
    if (prod) { pwrite(7, B3); pwrite(8, B0); pload(11, B3); pload(12, B0); }
    else      wincomp(4 + wq, b1 + (4 + wq) * 64, 6 + wq);
    BARL();                                            // pass 3
    if (prod) { pwrite(9, B1); pwrite(10, B2); pload(13, B1); pload(14, B2); }
    else      wincomp(6 + wq, b1 + (6 + wq) * 64, 8 + wq);
    BARL(); l2group(1);
    BARL();                                            // pass 4
    if (prod) { pwrite(11, B3); pwrite(12, B0); pload(15, B3); pload(16, B0); }
    else      wincomp(8 + wq, b1 + (8 + wq) * 64, 10 + wq);
    BARL();                                            // pass 5
    if (prod) { pwrite(13, B1); pwrite(14, B2); }
    else      wincomp(10 + wq, b1 + (10 + wq) * 64, 12 + wq);
    BARL(); l2group(2);
    BARL();                                            // pass 6
    if (prod) { pwrite(15, B3); pwrite(16, B0); }
    else      wincomp(12 + wq, b1 + (12 + wq) * 64, 14);   // prefetch win14 A
    BARL();                                            // pass 7: chunks 14-16 ready
    if (!prod) {
        win14c(q >> 2); win14c(2 + (q >> 2));
        y16c(q >> 2);   y16c(2 + (q >> 2));
    }
    BARL(); l2group(3);
    BARL();                                            // z complete

    // ---- layer 3: all 16 waves; (t, rh2) jobs; pool -> ps (aliases dead ring) ----
    {
        float* psp = (float*)sh;
        auto l3job = [&](int t, int rh2) {
            const _Float16* A = ws + 335872 + t * 4096;
            f32x4 acc = {0.f,0.f,0.f,0.f};
            #pragma unroll
            for (int kk = 0; kk < 8; ++kk) {
                f16x8 B  = *(const f16x8*)&sh[57856 + (16 * rh2 + r) * 264 + 32 * kk + 8 * kg];
                f16x8 Af = *(const f16x8*)(A + kk * 512 + l * 8);
                acc = MFMA16(Af, B, acc);
            }
            float p[10];
            #pragma unroll
            for (int c = 0; c < 10; ++c) p[c] = 0.f;
            #pragma unroll
            for (int tt = 0; tt < 4; ++tt) {
                int o = 16 * t + 4 * kg + tt;
                if (o < 260) p[(unsigned)o / 26u] += fmaxf(acc[tt] + b3[o], 0.f);
            }
            #pragma unroll
            for (int c = 0; c < 10; ++c) {
                p[c] += __shfl_xor(p[c], 16);
                p[c] += __shfl_xor(p[c], 32);
            }
            if (kg == 0) {
                #pragma unroll
                for (int c = 0; c < 10; ++c)
                    psp[t * 640 + (16 * rh2 + r) * 10 + c] = p[c];
            }
        };
        l3job((q >> 2),      q & 3);
        l3job(4 + (q >> 2),  q & 3);
        l3job(8 + (q >> 2),  q & 3);
        l3job(12 + (q >> 2), q & 3);
        if (q < 4) l3job(16, q);
    }
    BARL();                                            // ps in

    // ---- final: threads 0..63 = rows; sum 17 tiles; softmax; out ----
    if (tid < 64) {
        const float* psp = (const float*)sh;
        float v[10];
        #pragma unroll
        for (int c = 0; c < 10; ++c) {
            float s = 0.f;
            #pragma unroll
            for (int t = 0; t < 17; ++t) s += psp[t * 640 + tid * 10 + c];
            v[c] = s;
        }
        float mx = v[0];
        #pragma unroll
        for (int c = 1; c < 10; ++c) mx = fmaxf(mx, v[c]);
        float e[10], se = 0.f;
        #pragma unroll
        for (int c = 0; c < 10; ++c) { e[c] = expf(v[c] - mx); se += e[c]; }
        float inv = 1.f / se;
        float* orow = out + (size_t)(wg * 64 + tid) * 10;
        #pragma unroll
        for (int c = 0; c < 10; ++c) orow[c] = e[c] * inv;
    }
#undef BARL
}

extern "C" void kernel_launch(void* const* d_in, const int* in_sizes, int n_in,
                              void* d_out, int out_size, void* d_ws, size_t ws_size,
                              hipStream_t stream)
{
    const float* x   = (const float*)d_in[0];
    const float* W1  = (const float*)d_in[1];
    const float* b1  = (const float*)d_in[2];
    const float* W16 = (const float*)d_in[3];
    const float* b16 = (const float*)d_in[4];
    const float* W2  = (const float*)d_in[5];
    const float* b2  = (const float*)d_in[6];
    const float* W3  = (const float*)d_in[7];
    const float* b3  = (const float*)d_in[8];
    float*    out = (float*)d_out;
    _Float16* ws  = (_Float16*)d_ws;

    tea_prep<<<1584, 256, 0, stream>>>(W1, W16, W2, W3, ws);
    tea_dma <<<256, 1024, 0, stream>>>(x, b1, b16, b2, b3, ws, out);
}